// Round 1
// baseline (439.269 us; speedup 1.0000x reference)
//
#include <hip/hip_runtime.h>

#define DEV __device__ __forceinline__

typedef __attribute__((ext_vector_type(8))) short bf8;   // 8 x bf16 (4 VGPRs)
typedef __attribute__((ext_vector_type(4))) float f4;    // MFMA accumulator

DEV unsigned short f2bf(float f) {
  unsigned int u = __float_as_uint(f);
  u += 0x7FFFu + ((u >> 16) & 1u);   // round-to-nearest-even
  return (unsigned short)(u >> 16);
}

// ---------------------------------------------------------------------------
// GEMM: C[M,N] = A[M,K] @ B[N,K]^T  (+bias) (+relu) (+resid), bf16 in, f32 acc
// 128x128 tile, BK=32, 4 waves (2x2), 4x4 16x16x32 MFMA frags per wave.
// LDS XOR-swizzle ((row>>1)&3)<<3 on 8-elem groups; global source pre-swizzled
// so global_load_lds (linear dest) + swizzled ds_read round-trips correctly.
// ---------------------------------------------------------------------------
template<bool BIAS, bool RELU, bool RESID, bool OUTBF>
__global__ __launch_bounds__(256) void gemm_bt(
    const unsigned short* __restrict__ A, const unsigned short* __restrict__ B,
    const float* __restrict__ bias, const float* __restrict__ resid,
    void* __restrict__ Cout, int M, int N, int K)
{
  __shared__ unsigned short Al[128 * 32];
  __shared__ unsigned short Bl[128 * 32];
  const int t = threadIdx.x;
  const int w = t >> 6, l = t & 63;
  const int wr = w >> 1, wc = w & 1;
  const int m0 = blockIdx.y * 128, n0 = blockIdx.x * 128;

  const f4 fz = {0.f, 0.f, 0.f, 0.f};
  f4 acc[4][4];
#pragma unroll
  for (int i = 0; i < 4; ++i)
#pragma unroll
    for (int j = 0; j < 4; ++j) acc[i][j] = fz;

  for (int k0 = 0; k0 < K; k0 += 32) {
#pragma unroll
    for (int i = 0; i < 2; ++i) {
      const int row = i * 64 + w * 16 + (l >> 2);           // row within tile
      const int csw = ((l & 3) * 8) ^ (((row >> 1) & 3) << 3); // pre-swizzled src col
      const unsigned short* ga = A + (size_t)(m0 + row) * K + k0 + csw;
      const unsigned short* gb = B + (size_t)(n0 + row) * K + k0 + csw;
      __builtin_amdgcn_global_load_lds(
          (const __attribute__((address_space(1))) void*)ga,
          (__attribute__((address_space(3))) void*)(&Al[i * 2048 + w * 512 + l * 8]),
          16, 0, 0);
      __builtin_amdgcn_global_load_lds(
          (const __attribute__((address_space(1))) void*)gb,
          (__attribute__((address_space(3))) void*)(&Bl[i * 2048 + w * 512 + l * 8]),
          16, 0, 0);
    }
    __syncthreads();   // drains vmcnt for global_load_lds

    bf8 af[4], bg[4];
#pragma unroll
    for (int am = 0; am < 4; ++am) {
      const int row = wr * 64 + am * 16 + (l & 15);
      const int col = ((l >> 4) * 8) ^ (((row >> 1) & 3) << 3);
      af[am] = *(const bf8*)&Al[row * 32 + col];
    }
#pragma unroll
    for (int bn = 0; bn < 4; ++bn) {
      const int row = wc * 64 + bn * 16 + (l & 15);
      const int col = ((l >> 4) * 8) ^ (((row >> 1) & 3) << 3);
      bg[bn] = *(const bf8*)&Bl[row * 32 + col];
    }
#pragma unroll
    for (int am = 0; am < 4; ++am)
#pragma unroll
      for (int bn = 0; bn < 4; ++bn)
        acc[am][bn] = __builtin_amdgcn_mfma_f32_16x16x32_bf16(
            af[am], bg[bn], acc[am][bn], 0, 0, 0);
    __syncthreads();   // protect LDS from next iteration's stage
  }

  // epilogue: C layout col = lane&15, row = (lane>>4)*4 + reg
#pragma unroll
  for (int bn = 0; bn < 4; ++bn) {
    const int col = n0 + wc * 64 + bn * 16 + (l & 15);
    float bv = 0.f;
    if (BIAS) bv = bias[col];
#pragma unroll
    for (int am = 0; am < 4; ++am) {
#pragma unroll
      for (int r = 0; r < 4; ++r) {
        const int row = m0 + wr * 64 + am * 16 + ((l >> 4) * 4) + r;
        float v = acc[am][bn][r] + bv;
        if (RELU) v = fmaxf(v, 0.f);
        if (RESID) v += resid[(size_t)row * N + col];
        if (OUTBF) ((unsigned short*)Cout)[(size_t)row * N + col] = f2bf(v);
        else       ((float*)Cout)[(size_t)row * N + col] = v;
      }
    }
  }
}

// ---------------------------------------------------------------------------
// Causal flash attention. qkv: [B*S, 3072] bf16 (q|k|v, head h at cols h*64).
// Block = 256 thr = 4 waves; 64-query tile (16 q-rows per wave); 32-key steps.
// QK^T and PV via 16x16x32 bf16 MFMA; online softmax with shfl row-reduce.
// Softmax scale 1/8 pre-folded into wq. ctx out: [B*S, 1024] bf16.
// ---------------------------------------------------------------------------
__global__ __launch_bounds__(256) void attn_kernel(
    const unsigned short* __restrict__ qkv, unsigned short* __restrict__ ctx)
{
  __shared__ unsigned short Qs[64 * 64];   // swizzle (row&7)<<3
  __shared__ unsigned short Ks[32 * 64];   // swizzle (row&7)<<3
  __shared__ unsigned short Vt[64 * 32];   // V^T, swizzle ((d>>1)&3)<<3
  __shared__ unsigned short Ps[4][16 * 32];// per-wave P, swizzle ((q>>1)&3)<<3

  const int t = threadIdx.x;
  const int w = t >> 6, l = t & 63;
  const int qt0 = blockIdx.x * 64;
  const int h = blockIdx.y, b = blockIdx.z;
  const size_t RS = 3072;
  const unsigned short* qb = qkv + (size_t)b * 2048 * RS + h * 64;
  const unsigned short* kb = qb + 1024;
  const unsigned short* vb = qb + 2048;

  // stage Q tile (64x64)
#pragma unroll
  for (int i = 0; i < 2; ++i) {
    const int t2 = t + i * 256;
    const int row = t2 >> 3, c8 = (t2 & 7) * 8;
    uint4 d = *(const uint4*)(qb + (size_t)(qt0 + row) * RS + c8);
    *(uint4*)&Qs[(row * 64 + c8) ^ ((row & 7) << 3)] = d;
  }
  __syncthreads();

  bf8 qf[2];
  {
    const int row = w * 16 + (l & 15);
#pragma unroll
    for (int kk = 0; kk < 2; ++kk) {
      const int c = kk * 32 + ((l >> 4) * 8);
      qf[kk] = *(const bf8*)&Qs[row * 64 + (c ^ ((row & 7) << 3))];
    }
  }

  const f4 fz = {0.f, 0.f, 0.f, 0.f};
  f4 acc[4];
#pragma unroll
  for (int i = 0; i < 4; ++i) acc[i] = fz;
  float m_[4] = {-1e30f, -1e30f, -1e30f, -1e30f};
  float l_[4] = {0.f, 0.f, 0.f, 0.f};
  const int qbase = qt0 + w * 16 + ((l >> 4) * 4);

  for (int kb0 = 0; kb0 < qt0 + 64; kb0 += 32) {
    __syncthreads();   // previous iteration's reads done before overwrite
    {
      const int row = t >> 3, c8 = (t & 7) * 8;
      uint4 dk = *(const uint4*)(kb + (size_t)(kb0 + row) * RS + c8);
      *(uint4*)&Ks[(row * 64 + c8) ^ ((row & 7) << 3)] = dk;
      uint4 dv = *(const uint4*)(vb + (size_t)(kb0 + row) * RS + c8);
      const unsigned short* pv = (const unsigned short*)&dv;
#pragma unroll
      for (int i = 0; i < 8; ++i) {
        const int dd = c8 + i;
        Vt[(dd * 32 + row) ^ (((dd >> 1) & 3) << 3)] = pv[i];
      }
    }
    __syncthreads();

    // S = Q @ K^T : s0 keys [kb0,kb0+16), s1 keys [kb0+16,kb0+32)
    f4 s0 = fz, s1 = fz;
#pragma unroll
    for (int kk = 0; kk < 2; ++kk) {
      const int c = kk * 32 + ((l >> 4) * 8);
      const int r0 = l & 15, r1 = 16 + (l & 15);
      bf8 k0f = *(const bf8*)&Ks[r0 * 64 + (c ^ ((r0 & 7) << 3))];
      bf8 k1f = *(const bf8*)&Ks[r1 * 64 + (c ^ ((r1 & 7) << 3))];
      s0 = __builtin_amdgcn_mfma_f32_16x16x32_bf16(qf[kk], k0f, s0, 0, 0, 0);
      s1 = __builtin_amdgcn_mfma_f32_16x16x32_bf16(qf[kk], k1f, s1, 0, 0, 0);
    }

    // online softmax per query row (rows live in reg r + lane>>4 group)
    const int k0g = kb0 + (l & 15), k1g = k0g + 16;
    float p0[4], p1[4];
#pragma unroll
    for (int r = 0; r < 4; ++r) {
      const int qg = qbase + r;
      float v0 = (k0g <= qg) ? s0[r] : -1e30f;
      float v1 = (k1g <= qg) ? s1[r] : -1e30f;
      float mx = fmaxf(v0, v1);
      mx = fmaxf(mx, __shfl_xor(mx, 1));
      mx = fmaxf(mx, __shfl_xor(mx, 2));
      mx = fmaxf(mx, __shfl_xor(mx, 4));
      mx = fmaxf(mx, __shfl_xor(mx, 8));
      const float mn = fmaxf(m_[r], mx);
      const float alpha = __expf(m_[r] - mn);
      p0[r] = __expf(v0 - mn);
      p1[r] = __expf(v1 - mn);
      float rs = p0[r] + p1[r];
      rs += __shfl_xor(rs, 1);
      rs += __shfl_xor(rs, 2);
      rs += __shfl_xor(rs, 4);
      rs += __shfl_xor(rs, 8);
      l_[r] = alpha * l_[r] + rs;
      m_[r] = mn;
      acc[0][r] *= alpha; acc[1][r] *= alpha;
      acc[2][r] *= alpha; acc[3][r] *= alpha;
    }

    // stage P (bf16) into this wave's LDS slice
#pragma unroll
    for (int r = 0; r < 4; ++r) {
      const int q = ((l >> 4) * 4) + r;
      const int sw = ((q >> 1) & 3) << 3;
      Ps[w][(q * 32 + (l & 15)) ^ sw]      = f2bf(p0[r]);
      Ps[w][(q * 32 + 16 + (l & 15)) ^ sw] = f2bf(p1[r]);
    }

    // ctx += P @ V  (A = P rows, B = Vt rows)
    {
      const int pr = l & 15;
      const int pc = ((l >> 4) * 8) ^ (((pr >> 1) & 3) << 3);
      bf8 pf = *(const bf8*)&Ps[w][pr * 32 + pc];
#pragma unroll
      for (int dt = 0; dt < 4; ++dt) {
        const int vr = dt * 16 + (l & 15);
        const int vc = ((l >> 4) * 8) ^ (((vr >> 1) & 3) << 3);
        bf8 vf = *(const bf8*)&Vt[vr * 32 + vc];
        acc[dt] = __builtin_amdgcn_mfma_f32_16x16x32_bf16(pf, vf, acc[dt], 0, 0, 0);
      }
    }
  }

#pragma unroll
  for (int dt = 0; dt < 4; ++dt)
#pragma unroll
    for (int r = 0; r < 4; ++r) {
      const int row = b * 2048 + qbase + r;
      const int col = h * 64 + dt * 16 + (l & 15);
      ctx[(size_t)row * 1024 + col] = f2bf(acc[dt][r] / l_[r]);
    }
}

// ---------------------------------------------------------------------------
// LayerNorm over rows of 1024 fp32 -> bf16. One block per row.
// ---------------------------------------------------------------------------
__global__ __launch_bounds__(256) void ln_kernel(
    const float* __restrict__ x, const float* __restrict__ sc,
    const float* __restrict__ sh, unsigned short* __restrict__ out)
{
  const int row = blockIdx.x, t = threadIdx.x;
  float4 v = ((const float4*)x)[(size_t)row * 256 + t];
  float s = v.x + v.y + v.z + v.w;
  float q = v.x * v.x + v.y * v.y + v.z * v.z + v.w * v.w;
#pragma unroll
  for (int off = 1; off < 64; off <<= 1) {
    s += __shfl_xor(s, off);
    q += __shfl_xor(q, off);
  }
  __shared__ float red[8];
  const int w = t >> 6, l = t & 63;
  if (l == 0) { red[w] = s; red[4 + w] = q; }
  __syncthreads();
  s = red[0] + red[1] + red[2] + red[3];
  q = red[4] + red[5] + red[6] + red[7];
  const float mean = s * (1.0f / 1024.0f);
  const float var = q * (1.0f / 1024.0f) - mean * mean;
  const float rstd = rsqrtf(var + 1e-5f);
  float4 scv = ((const float4*)sc)[t];
  float4 shv = ((const float4*)sh)[t];
  uint2 p;
  p.x = (unsigned int)f2bf(scv.x * (v.x - mean) * rstd + shv.x)
      | ((unsigned int)f2bf(scv.y * (v.y - mean) * rstd + shv.y) << 16);
  p.y = (unsigned int)f2bf(scv.z * (v.z - mean) * rstd + shv.z)
      | ((unsigned int)f2bf(scv.w * (v.w - mean) * rstd + shv.w) << 16);
  ((uint2*)out)[(size_t)row * 256 + t] = p;
}

// fp32 -> bf16 (optionally scaled) conversion, 4 elems/thread
__global__ __launch_bounds__(256) void cvt_kernel(
    const float* __restrict__ src, unsigned short* __restrict__ dst,
    int n4, float scale)
{
  int i = blockIdx.x * 256 + threadIdx.x;
  const int stride = gridDim.x * 256;
  for (; i < n4; i += stride) {
    float4 v = ((const float4*)src)[i];
    uint2 p;
    p.x = (unsigned int)f2bf(v.x * scale) | ((unsigned int)f2bf(v.y * scale) << 16);
    p.y = (unsigned int)f2bf(v.z * scale) | ((unsigned int)f2bf(v.w * scale) << 16);
    ((uint2*)dst)[i] = p;
  }
}

// ---------------------------------------------------------------------------
extern "C" void kernel_launch(void* const* d_in, const int* in_sizes, int n_in,
                              void* d_out, int out_size, void* d_ws, size_t ws_size,
                              hipStream_t stream)
{
  const float* x    = (const float*)d_in[0];
  const float* wq   = (const float*)d_in[1];
  const float* wk   = (const float*)d_in[2];
  const float* wv   = (const float*)d_in[3];
  const float* wo   = (const float*)d_in[4];
  const float* bo   = (const float*)d_in[5];
  const float* ln1s = (const float*)d_in[6];
  const float* ln1b = (const float*)d_in[7];
  const float* ln2s = (const float*)d_in[8];
  const float* ln2b = (const float*)d_in[9];
  const float* w1   = (const float*)d_in[10];
  const float* b1   = (const float*)d_in[11];
  const float* w2   = (const float*)d_in[12];
  const float* b2   = (const float*)d_in[13];
  float* out = (float*)d_out;

  const int M = 4096; // B*S

  // workspace layout (~84 MB): bf16 buffers then fp32 h
  unsigned short* ws   = (unsigned short*)d_ws;
  unsigned short* lnb  = ws;                              // [4096,1024] ln1/ln2
  unsigned short* qkvw = lnb  + (size_t)4096 * 1024;      // [3072,1024] wq(.125)|wk|wv
  unsigned short* wob  = qkvw + (size_t)3072 * 1024;      // [1024,1024]
  unsigned short* w1b  = wob  + (size_t)1024 * 1024;      // [4096,1024]
  unsigned short* w2b  = w1b  + (size_t)4096 * 1024;      // [1024,4096]
  unsigned short* qkvb = w2b  + (size_t)4096 * 1024;      // [4096,3072]; later y1 [4096,4096]
  unsigned short* ctxb = qkvb + (size_t)4096 * 3072;      // [4096,1024]
  float* hf = (float*)(ctxb + (size_t)4096 * 1024);       // [4096,1024] fp32

  // weight conversions (1/sqrt(64) folded into wq)
  cvt_kernel<<<1024, 256, 0, stream>>>(wq, qkvw,                        (1024 * 1024) / 4, 0.125f);
  cvt_kernel<<<1024, 256, 0, stream>>>(wk, qkvw + (size_t)1024 * 1024,  (1024 * 1024) / 4, 1.0f);
  cvt_kernel<<<1024, 256, 0, stream>>>(wv, qkvw + (size_t)2048 * 1024,  (1024 * 1024) / 4, 1.0f);
  cvt_kernel<<<1024, 256, 0, stream>>>(wo, wob,                         (1024 * 1024) / 4, 1.0f);
  cvt_kernel<<<2048, 256, 0, stream>>>(w1, w1b, (4096 * 1024) / 4, 1.0f);
  cvt_kernel<<<2048, 256, 0, stream>>>(w2, w2b, (4096 * 1024) / 4, 1.0f);

  // ln1 = LN(x)
  ln_kernel<<<M, 256, 0, stream>>>(x, ln1s, ln1b, lnb);
  // qkv = ln1 @ [wq*0.125|wk|wv]^T
  gemm_bt<false, false, false, true><<<dim3(24, 32), 256, 0, stream>>>(
      lnb, qkvw, nullptr, nullptr, qkvb, M, 3072, 1024);
  // ctx = causal_attention(q,k,v)
  attn_kernel<<<dim3(32, 16, 2), 256, 0, stream>>>(qkvb, ctxb);
  // h = x + ctx @ wo^T + bo   (fp32)
  gemm_bt<true, false, true, false><<<dim3(8, 32), 256, 0, stream>>>(
      ctxb, wob, bo, x, hf, M, 1024, 1024);
  // ln2 = LN(h)
  ln_kernel<<<M, 256, 0, stream>>>(hf, ln2s, ln2b, lnb);
  // y1 = relu(ln2 @ w1^T + b1)  (bf16, reuses qkv region)
  gemm_bt<true, true, false, true><<<dim3(32, 32), 256, 0, stream>>>(
      lnb, w1b, b1, nullptr, qkvb, M, 4096, 1024);
  // out = h + y1 @ w2^T + b2
  gemm_bt<true, false, true, false><<<dim3(8, 32), 256, 0, stream>>>(
      qkvb, w2b, b2, hf, out, M, 1024, 4096);
}

// Round 2
// 318.685 us; speedup vs baseline: 1.3784x; 1.3784x over previous
//
#include <hip/hip_runtime.h>

#define DEV __device__ __forceinline__

typedef __attribute__((ext_vector_type(8))) short bf8;    // 8 x bf16 (4 VGPRs)
typedef __attribute__((ext_vector_type(4))) float f4;     // 16x16 MFMA acc
typedef __attribute__((ext_vector_type(16))) float f16x;  // 32x32 MFMA acc

DEV unsigned short f2bf(float f) {
  unsigned int u = __float_as_uint(f);
  u += 0x7FFFu + ((u >> 16) & 1u);   // round-to-nearest-even
  return (unsigned short)(u >> 16);
}
DEV unsigned int pk2(float a, float b) {
  return (unsigned int)f2bf(a) | ((unsigned int)f2bf(b) << 16);
}

// ---------------------------------------------------------------------------
// GEMM: C[M,N] = A[M,K] @ B[N,K]^T (+bias)(+relu)(+resid), bf16 in, f32 acc.
// 128x128 tile, BK=32, 4 waves (2x2), 4x4 16x16x32 MFMA frags per wave.
// WRVT: cols >=2048 (the V part of QKV) are written TRANSPOSED to vtout
//       laid out [b*16+h][64 d][2048 s]; cols <2048 go to Cout at stride ldc.
// ---------------------------------------------------------------------------
template<bool BIAS, bool RELU, bool RESID, bool OUTBF, bool WRVT>
__global__ __launch_bounds__(256) void gemm_bt(
    const unsigned short* __restrict__ A, const unsigned short* __restrict__ B,
    const float* __restrict__ bias, const float* __restrict__ resid,
    void* __restrict__ Cout, int M, int N, int K, int ldc,
    unsigned short* __restrict__ vtout)
{
  __shared__ unsigned short Al[128 * 32];
  __shared__ unsigned short Bl[128 * 32];
  const int t = threadIdx.x;
  const int w = t >> 6, l = t & 63;
  const int wr = w >> 1, wc = w & 1;
  const int m0 = blockIdx.y * 128, n0 = blockIdx.x * 128;

  const f4 fz = {0.f, 0.f, 0.f, 0.f};
  f4 acc[4][4];
#pragma unroll
  for (int i = 0; i < 4; ++i)
#pragma unroll
    for (int j = 0; j < 4; ++j) acc[i][j] = fz;

  for (int k0 = 0; k0 < K; k0 += 32) {
#pragma unroll
    for (int i = 0; i < 2; ++i) {
      const int row = i * 64 + w * 16 + (l >> 2);
      const int csw = ((l & 3) * 8) ^ (((row >> 1) & 3) << 3);
      const unsigned short* ga = A + (size_t)(m0 + row) * K + k0 + csw;
      const unsigned short* gb = B + (size_t)(n0 + row) * K + k0 + csw;
      __builtin_amdgcn_global_load_lds(
          (const __attribute__((address_space(1))) void*)ga,
          (__attribute__((address_space(3))) void*)(&Al[i * 2048 + w * 512 + l * 8]),
          16, 0, 0);
      __builtin_amdgcn_global_load_lds(
          (const __attribute__((address_space(1))) void*)gb,
          (__attribute__((address_space(3))) void*)(&Bl[i * 2048 + w * 512 + l * 8]),
          16, 0, 0);
    }
    __syncthreads();

    bf8 af[4], bg[4];
#pragma unroll
    for (int am = 0; am < 4; ++am) {
      const int row = wr * 64 + am * 16 + (l & 15);
      const int col = ((l >> 4) * 8) ^ (((row >> 1) & 3) << 3);
      af[am] = *(const bf8*)&Al[row * 32 + col];
    }
#pragma unroll
    for (int bn = 0; bn < 4; ++bn) {
      const int row = wc * 64 + bn * 16 + (l & 15);
      const int col = ((l >> 4) * 8) ^ (((row >> 1) & 3) << 3);
      bg[bn] = *(const bf8*)&Bl[row * 32 + col];
    }
#pragma unroll
    for (int am = 0; am < 4; ++am)
#pragma unroll
      for (int bn = 0; bn < 4; ++bn)
        acc[am][bn] = __builtin_amdgcn_mfma_f32_16x16x32_bf16(
            af[am], bg[bn], acc[am][bn], 0, 0, 0);
    __syncthreads();
  }

#pragma unroll
  for (int bn = 0; bn < 4; ++bn) {
    const int col = n0 + wc * 64 + bn * 16 + (l & 15);
    float bv = 0.f;
    if (BIAS) bv = bias[col];
    const bool isv = WRVT && (col >= 2048);
    const int hh = (col - 2048) >> 6, dd = (col - 2048) & 63;
#pragma unroll
    for (int am = 0; am < 4; ++am) {
#pragma unroll
      for (int r = 0; r < 4; ++r) {
        const int row = m0 + wr * 64 + am * 16 + ((l >> 4) * 4) + r;
        float v = acc[am][bn][r] + bv;
        if (RELU) v = fmaxf(v, 0.f);
        if (RESID) v += resid[(size_t)row * ldc + col];
        if (WRVT && isv) {
          const int bb = row >> 11, ss = row & 2047;
          vtout[((size_t)(bb * 16 + hh) * 64 + dd) * 2048 + ss] = f2bf(v);
        } else if (OUTBF) {
          ((unsigned short*)Cout)[(size_t)row * ldc + col] = f2bf(v);
        } else {
          ((float*)Cout)[(size_t)row * ldc + col] = v;
        }
      }
    }
  }
}

// ---------------------------------------------------------------------------
// Causal flash attention, swapped-operand 32x32 structure.
// qk: [4096][2048] bf16 (q|k per token; head h at cols h*64, k at +1024).
// vt: [32 bh][64 d][2048 s] bf16.   ctx out: [4096][1024] bf16.
// Block = 256 thr = 4 waves; wave owns 32 queries; KVBLK=64, double-buffered.
// S^T = mfma(K,Q): lane&31 = query col, keys in regs -> lane-local softmax
// (one shfl_xor(32) completes the 32-key row stats). P repacked in-register
// (pk2 + shfl_xor(32)) straight into O^T = mfma(V^T, P); alpha & 1/l are
// lane-local since O^T col = query. Heavy-first q-tile order (qt = 15-bx).
// ---------------------------------------------------------------------------
__global__ __launch_bounds__(256, 2) void attn_kernel(
    const unsigned short* __restrict__ qk, const unsigned short* __restrict__ vt,
    unsigned short* __restrict__ ctx)
{
  __shared__ unsigned short Ks[2][64 * 64];   // [keys][kdim], XOR-swizzled
  __shared__ unsigned short Vs[2][64 * 64];   // [d][keys],   XOR-swizzled

  const int t = threadIdx.x;
  const int w = t >> 6, l = t & 63;
  const int hi = l >> 5, q = l & 31;
  const int qt = 15 - (int)blockIdx.x;        // heavy-first
  const int h = blockIdx.y, b = blockIdx.z;
  const int q0b = qt * 128;
  const int q0w = q0b + w * 32;
  const unsigned short* qbase = qk + ((size_t)b * 2048) * 2048 + h * 64;
  const unsigned short* kbase = qbase + 1024;
  const unsigned short* vbase = vt + ((size_t)(b * 16 + h)) * 64 * 2048;

  // Q fragments (B operand): qf[ksl] = Q[q0w+q][ksl*16 + hi*8 .. +8]
  bf8 qf[4];
#pragma unroll
  for (int ksl = 0; ksl < 4; ++ksl)
    qf[ksl] = *(const bf8*)(qbase + (size_t)(q0w + q) * 2048 + ksl * 16 + hi * 8);

  f16x oacc[2];
#pragma unroll
  for (int dn = 0; dn < 2; ++dn)
#pragma unroll
    for (int i = 0; i < 16; ++i) oacc[dn][i] = 0.f;
  float m_ = -1e30f, l_ = 0.f;

  const int nit = 2 * qt + 2;

  auto STAGE = [&](int buf, int it) {
#pragma unroll
    for (int s = 0; s < 2; ++s) {
      const int row = s * 32 + (t >> 3);
      const int cb = (t & 7) * 16;                  // byte col in LDS (linear)
      const int sb = cb ^ ((row & 7) << 4);         // pre-swizzled global byte col
      __builtin_amdgcn_global_load_lds(
          (const __attribute__((address_space(1))) void*)
              (kbase + (size_t)(it * 64 + row) * 2048 + (sb >> 1)),
          (__attribute__((address_space(3))) void*)(&Ks[buf][row * 64 + (cb >> 1)]),
          16, 0, 0);
      __builtin_amdgcn_global_load_lds(
          (const __attribute__((address_space(1))) void*)
              (vbase + (size_t)row * 2048 + it * 64 + (sb >> 1)),
          (__attribute__((address_space(3))) void*)(&Vs[buf][row * 64 + (cb >> 1)]),
          16, 0, 0);
    }
  };

  STAGE(0, 0);
  __syncthreads();

  for (int it = 0; it < nit; ++it) {
    const int buf = it & 1;
    if (it + 1 < nit) STAGE(buf ^ 1, it + 1);
    const int kb0 = it * 64;

    if (kb0 <= q0w + 31) {                    // wave has unmasked work here
      const bool bdry = (kb0 + 63) > q0w;
#pragma unroll
      for (int sg = 0; sg < 2; ++sg) {
        // ---- S^T = K @ Q^T over kdim=64 (4 slices of 16) ----
        f16x sacc;
#pragma unroll
        for (int i = 0; i < 16; ++i) sacc[i] = 0.f;
#pragma unroll
        for (int ksl = 0; ksl < 4; ++ksl) {
          const int row = sg * 32 + q;        // key row (A operand: lane&31)
          const int cb = ((ksl * 16 + hi * 8) * 2) ^ ((row & 7) << 4);
          bf8 kf = *(const bf8*)((const char*)&Ks[buf][row * 64] + cb);
          sacc = __builtin_amdgcn_mfma_f32_32x32x16_bf16(kf, qf[ksl], sacc, 0, 0, 0);
        }
        // ---- causal mask + online softmax (lane-local; one cross-half shfl) ----
        float p[16];
        if (bdry) {
#pragma unroll
          for (int i = 0; i < 16; ++i) {
            const int key = kb0 + sg * 32 + (i & 3) + 8 * (i >> 2) + 4 * hi;
            p[i] = (key <= q0w + q) ? sacc[i] : -1e30f;
          }
        } else {
#pragma unroll
          for (int i = 0; i < 16; ++i) p[i] = sacc[i];
        }
        float mx = p[0];
#pragma unroll
        for (int i = 1; i < 16; ++i) mx = fmaxf(mx, p[i]);
        mx = fmaxf(mx, __shfl_xor(mx, 32));
        const float mn = fmaxf(m_, mx);
        const float alpha = __expf(m_ - mn);
        m_ = mn;
        float rs = 0.f;
#pragma unroll
        for (int i = 0; i < 16; ++i) { p[i] = __expf(p[i] - mn); rs += p[i]; }
        rs += __shfl_xor(rs, 32);
        l_ = alpha * l_ + rs;
#pragma unroll
        for (int dn = 0; dn < 2; ++dn)
#pragma unroll
          for (int i = 0; i < 16; ++i) oacc[dn][i] *= alpha;

        // ---- pack P to bf16 words: wds[2m+c] = keys (8m+4hi+2c, +1) ----
        unsigned int wds[8];
#pragma unroll
        for (int m = 0; m < 4; ++m) {
          wds[m * 2]     = pk2(p[4 * m], p[4 * m + 1]);
          wds[m * 2 + 1] = pk2(p[4 * m + 2], p[4 * m + 3]);
        }
        // ---- O^T += V^T @ P over this sg's 32 keys (2 slices of 16) ----
#pragma unroll
        for (int kq = 0; kq < 2; ++kq) {
          // exchange: hi=0 sends slice 2kq+1 words, hi=1 sends slice 2kq words
          unsigned int x0 = __shfl_xor((int)(hi ? wds[4 * kq]     : wds[4 * kq + 2]), 32);
          unsigned int x1 = __shfl_xor((int)(hi ? wds[4 * kq + 1] : wds[4 * kq + 3]), 32);
          unsigned int pw0 = hi ? x0 : wds[4 * kq];
          unsigned int pw1 = hi ? x1 : wds[4 * kq + 1];
          unsigned int pw2 = hi ? wds[4 * kq + 2] : x0;
          unsigned int pw3 = hi ? wds[4 * kq + 3] : x1;
          union { unsigned int u[4]; bf8 v; } pu;
          pu.u[0] = pw0; pu.u[1] = pw1; pu.u[2] = pw2; pu.u[3] = pw3;
          const bf8 pf = pu.v;
#pragma unroll
          for (int dn = 0; dn < 2; ++dn) {
            const int row = dn * 32 + q;      // d row (A operand: lane&31)
            const int cb = ((sg * 32 + kq * 16 + hi * 8) * 2) ^ ((row & 7) << 4);
            bf8 vf = *(const bf8*)((const char*)&Vs[buf][row * 64] + cb);
            oacc[dn] = __builtin_amdgcn_mfma_f32_32x32x16_bf16(vf, pf, oacc[dn], 0, 0, 0);
          }
        }
      }
    }
    __syncthreads();
  }

  // epilogue: lane (hi,q) reg i of oacc[dn] = O^T[d = dn*32 + (i&3)+8*(i>>2)+4hi][q]
  const float inv = 1.0f / l_;
  unsigned short* crow = ctx + ((size_t)(b * 2048 + q0w + q)) * 1024 + h * 64;
#pragma unroll
  for (int dn = 0; dn < 2; ++dn)
#pragma unroll
    for (int m = 0; m < 4; ++m) {
      const int d0 = dn * 32 + 8 * m + 4 * hi;
      *(unsigned int*)(crow + d0)     = pk2(oacc[dn][4 * m] * inv, oacc[dn][4 * m + 1] * inv);
      *(unsigned int*)(crow + d0 + 2) = pk2(oacc[dn][4 * m + 2] * inv, oacc[dn][4 * m + 3] * inv);
    }
}

// ---------------------------------------------------------------------------
// LayerNorm over rows of 1024 fp32 -> bf16. One block per row.
// ---------------------------------------------------------------------------
__global__ __launch_bounds__(256) void ln_kernel(
    const float* __restrict__ x, const float* __restrict__ sc,
    const float* __restrict__ sh, unsigned short* __restrict__ out)
{
  const int row = blockIdx.x, t = threadIdx.x;
  float4 v = ((const float4*)x)[(size_t)row * 256 + t];
  float s = v.x + v.y + v.z + v.w;
  float q = v.x * v.x + v.y * v.y + v.z * v.z + v.w * v.w;
#pragma unroll
  for (int off = 1; off < 64; off <<= 1) {
    s += __shfl_xor(s, off);
    q += __shfl_xor(q, off);
  }
  __shared__ float red[8];
  const int w = t >> 6, l = t & 63;
  if (l == 0) { red[w] = s; red[4 + w] = q; }
  __syncthreads();
  s = red[0] + red[1] + red[2] + red[3];
  q = red[4] + red[5] + red[6] + red[7];
  const float mean = s * (1.0f / 1024.0f);
  const float var = q * (1.0f / 1024.0f) - mean * mean;
  const float rstd = rsqrtf(var + 1e-5f);
  float4 scv = ((const float4*)sc)[t];
  float4 shv = ((const float4*)sh)[t];
  uint2 p;
  p.x = pk2(scv.x * (v.x - mean) * rstd + shv.x, scv.y * (v.y - mean) * rstd + shv.y);
  p.y = pk2(scv.z * (v.z - mean) * rstd + shv.z, scv.w * (v.w - mean) * rstd + shv.w);
  ((uint2*)out)[(size_t)row * 256 + t] = p;
}

// fp32 -> bf16 (optionally scaled) conversion, 4 elems/thread
__global__ __launch_bounds__(256) void cvt_kernel(
    const float* __restrict__ src, unsigned short* __restrict__ dst,
    int n4, float scale)
{
  int i = blockIdx.x * 256 + threadIdx.x;
  const int stride = gridDim.x * 256;
  for (; i < n4; i += stride) {
    float4 v = ((const float4*)src)[i];
    uint2 p;
    p.x = pk2(v.x * scale, v.y * scale);
    p.y = pk2(v.z * scale, v.w * scale);
    ((uint2*)dst)[i] = p;
  }
}

// ---------------------------------------------------------------------------
extern "C" void kernel_launch(void* const* d_in, const int* in_sizes, int n_in,
                              void* d_out, int out_size, void* d_ws, size_t ws_size,
                              hipStream_t stream)
{
  const float* x    = (const float*)d_in[0];
  const float* wq   = (const float*)d_in[1];
  const float* wk   = (const float*)d_in[2];
  const float* wv   = (const float*)d_in[3];
  const float* wo   = (const float*)d_in[4];
  const float* bo   = (const float*)d_in[5];
  const float* ln1s = (const float*)d_in[6];
  const float* ln1b = (const float*)d_in[7];
  const float* ln2s = (const float*)d_in[8];
  const float* ln2b = (const float*)d_in[9];
  const float* w1   = (const float*)d_in[10];
  const float* b1   = (const float*)d_in[11];
  const float* w2   = (const float*)d_in[12];
  const float* b2   = (const float*)d_in[13];
  float* out = (float*)d_out;

  const int M = 4096; // B*S

  // workspace (~80 MB)
  unsigned short* ws   = (unsigned short*)d_ws;
  unsigned short* lnb  = ws;                              // [4096,1024]
  unsigned short* qkvw = lnb  + (size_t)4096 * 1024;      // [3072,1024] wq(.125)|wk|wv
  unsigned short* wob  = qkvw + (size_t)3072 * 1024;      // [1024,1024]
  unsigned short* w1b  = wob  + (size_t)1024 * 1024;      // [4096,1024]
  unsigned short* w2b  = w1b  + (size_t)4096 * 1024;      // [1024,4096]
  unsigned short* qkb  = w2b  + (size_t)4096 * 1024;      // [4096,2048] q|k; y1 [4096,4096]
  unsigned short* vtb  = qkb  + (size_t)4096 * 2048;      // [32,64,2048] V^T
  unsigned short* ctxb = vtb  + (size_t)32 * 64 * 2048;   // [4096,1024]
  float* hf = (float*)(ctxb + (size_t)4096 * 1024);       // [4096,1024] fp32

  // weight conversions (1/sqrt(64) folded into wq)
  cvt_kernel<<<1024, 256, 0, stream>>>(wq, qkvw,                       (1024 * 1024) / 4, 0.125f);
  cvt_kernel<<<1024, 256, 0, stream>>>(wk, qkvw + (size_t)1024 * 1024, (1024 * 1024) / 4, 1.0f);
  cvt_kernel<<<1024, 256, 0, stream>>>(wv, qkvw + (size_t)2048 * 1024, (1024 * 1024) / 4, 1.0f);
  cvt_kernel<<<1024, 256, 0, stream>>>(wo, wob,                        (1024 * 1024) / 4, 1.0f);
  cvt_kernel<<<2048, 256, 0, stream>>>(w1, w1b, (4096 * 1024) / 4, 1.0f);
  cvt_kernel<<<2048, 256, 0, stream>>>(w2, w2b, (4096 * 1024) / 4, 1.0f);

  // ln1 = LN(x)
  ln_kernel<<<M, 256, 0, stream>>>(x, ln1s, ln1b, lnb);
  // q|k -> qkb (stride 2048), v -> vtb transposed
  gemm_bt<false, false, false, true, true><<<dim3(24, 32), 256, 0, stream>>>(
      lnb, qkvw, nullptr, nullptr, qkb, M, 3072, 1024, 2048, vtb);
  // ctx = causal_attention(q,k,v)
  attn_kernel<<<dim3(16, 16, 2), 256, 0, stream>>>(qkb, vtb, ctxb);
  // h = x + ctx @ wo^T + bo   (fp32)
  gemm_bt<true, false, true, false, false><<<dim3(8, 32), 256, 0, stream>>>(
      ctxb, wob, bo, x, hf, M, 1024, 1024, 1024, nullptr);
  // ln2 = LN(h)
  ln_kernel<<<M, 256, 0, stream>>>(hf, ln2s, ln2b, lnb);
  // y1 = relu(ln2 @ w1^T + b1)  (bf16, reuses qkb region)
  gemm_bt<true, true, false, true, false><<<dim3(32, 32), 256, 0, stream>>>(
      lnb, w1b, b1, nullptr, qkb, M, 4096, 1024, 4096, nullptr);
  // out = h + y1 @ w2^T + b2
  gemm_bt<true, false, true, false, false><<<dim3(8, 32), 256, 0, stream>>>(
      qkb, w2b, b2, hf, out, M, 1024, 4096, 1024, nullptr);
}

// Round 3
// 286.296 us; speedup vs baseline: 1.5343x; 1.1131x over previous
//
#include <hip/hip_runtime.h>

#define DEV __device__ __forceinline__

typedef __attribute__((ext_vector_type(8))) short bf8;    // 8 x bf16 (4 VGPRs)
typedef __attribute__((ext_vector_type(4))) float f4;     // 16x16 MFMA acc
typedef __attribute__((ext_vector_type(16))) float f16x;  // 32x32 MFMA acc

DEV unsigned short f2bf(float f) {
  unsigned int u = __float_as_uint(f);
  u += 0x7FFFu + ((u >> 16) & 1u);   // round-to-nearest-even
  return (unsigned short)(u >> 16);
}
DEV unsigned int pk2(float a, float b) {
  return (unsigned int)f2bf(a) | ((unsigned int)f2bf(b) << 16);
}

// XCD-aware bijective block swizzle + 4-wide N supertiling.
// Requires gridDim.x == nxt*nyt and nxt*nyt % 8 == 0 and nxt % 4 == 0.
// Returns (mtile, ntile). Consecutive work-ids within one XCD chunk cover an
// (cpx/4)-M x 4-N region -> A-panel reuse in the XCD-private L2.
DEV int2 swz_tile(int ob, int nxt, int nyt) {
  const int nb = nxt * nyt;
  const int cpx = nb >> 3;
  const int W = (ob & 7) * cpx + (ob >> 3);
  const int scw = 4 * nyt;
  const int sc = W / scw, rem = W - sc * scw;
  return make_int2(rem >> 2, sc * 4 + (rem & 3));
}

// ---------------------------------------------------------------------------
// 256x256-tile GEMM: C[M,N] = A[M,K] @ B[N,K]^T (+bias)(+relu), bf16, f32 acc.
// 512 thr = 8 waves (2x4); per-wave 128x64 out = 8x4 16x16x32 MFMA frags.
// BK=64, 2 LDS slots (128 KiB), 2-phase: stage K-tile T+1 before computing T,
// one __syncthreads per tile (implicit vmcnt(0) drains the 8 in-flight loads).
// LDS rows are 128B; reads XOR-swizzled by (row&7)<<4 (2-way = free); global
// source pre-swizzled so linear-dest global_load_lds round-trips correctly.
// WRVT: cols >= 2048 (V of QKV) written transposed to vtout [b*16+h][64][2048].
// ---------------------------------------------------------------------------
template<bool BIAS, bool RELU, bool OUTBF, bool WRVT>
__global__ __launch_bounds__(512, 2) void gemm_bt256(
    const unsigned short* __restrict__ A, const unsigned short* __restrict__ B,
    const float* __restrict__ bias, void* __restrict__ Cout,
    int M, int N, int K, int ldc, unsigned short* __restrict__ vtout, int nyt)
{
  __shared__ unsigned short Sl[2][2][256 * 64];   // [slot][A=0/B=1][row*64+col]
  const int t = threadIdx.x;
  const int w = t >> 6, l = t & 63;
  const int wr = w >> 2, wc = w & 3;              // 2 x 4 wave grid
  int2 tt = swz_tile((int)blockIdx.x, N >> 8, nyt);
  const int m0 = tt.x * 256, n0 = tt.y * 256;

  // staging constants: wave-load i covers rows w*32+i*8 .. +8, 16B per lane
  const int srow = w * 32 + (l >> 3);
  const int scol = 8 * ((l & 7) ^ (l >> 3));      // pre-swizzled elem col
  const unsigned short* Ab = A + (size_t)(m0 + srow) * K + scol;
  const unsigned short* Bb = B + (size_t)(n0 + srow) * K + scol;
  const int sdst = w * 2048 + l * 8;              // + i*512 (elems)

  auto STAGE = [&](int slot, int kt) {
#pragma unroll
    for (int i = 0; i < 4; ++i) {
      __builtin_amdgcn_global_load_lds(
          (const __attribute__((address_space(1))) void*)(Ab + (size_t)i * 8 * K + kt * 64),
          (__attribute__((address_space(3))) void*)(&Sl[slot][0][sdst + i * 512]), 16, 0, 0);
      __builtin_amdgcn_global_load_lds(
          (const __attribute__((address_space(1))) void*)(Bb + (size_t)i * 8 * K + kt * 64),
          (__attribute__((address_space(3))) void*)(&Sl[slot][1][sdst + i * 512]), 16, 0, 0);
    }
  };

  const f4 fz = {0.f, 0.f, 0.f, 0.f};
  f4 acc[8][4];
#pragma unroll
  for (int i = 0; i < 8; ++i)
#pragma unroll
    for (int j = 0; j < 4; ++j) acc[i][j] = fz;

  const int NT = K >> 6;
  STAGE(0, 0);
  __syncthreads();

  for (int T = 0; T < NT; ++T) {
    if (T + 1 < NT) STAGE((T + 1) & 1, T + 1);
    const int sl = T & 1;
#pragma unroll
    for (int ks = 0; ks < 2; ++ks) {
      const int cb = (ks * 64 + ((l >> 4) * 16)) ^ ((l & 7) << 4);  // bytes in row
      bf8 af[8], bg[4];
#pragma unroll
      for (int m = 0; m < 8; ++m)
        af[m] = *(const bf8*)((const char*)&Sl[sl][0][(wr * 128 + m * 16 + (l & 15)) * 64] + cb);
#pragma unroll
      for (int n = 0; n < 4; ++n)
        bg[n] = *(const bf8*)((const char*)&Sl[sl][1][(wc * 64 + n * 16 + (l & 15)) * 64] + cb);
      __builtin_amdgcn_s_setprio(1);
#pragma unroll
      for (int m = 0; m < 8; ++m)
#pragma unroll
        for (int n = 0; n < 4; ++n)
          acc[m][n] = __builtin_amdgcn_mfma_f32_16x16x32_bf16(af[m], bg[n], acc[m][n], 0, 0, 0);
      __builtin_amdgcn_s_setprio(0);
    }
    __syncthreads();
  }

  // epilogue: frag C layout col = lane&15, row = (lane>>4)*4 + reg
#pragma unroll
  for (int n = 0; n < 4; ++n) {
    const int col = n0 + wc * 64 + n * 16 + (l & 15);
    float bv = 0.f;
    if (BIAS) bv = bias[col];
    const bool isv = WRVT && (col >= 2048);
    const int hh = (col - 2048) >> 6, dd = (col - 2048) & 63;
#pragma unroll
    for (int m = 0; m < 8; ++m) {
#pragma unroll
      for (int r = 0; r < 4; ++r) {
        const int row = m0 + wr * 128 + m * 16 + ((l >> 4) * 4) + r;
        float v = acc[m][n][r] + bv;
        if (RELU) v = fmaxf(v, 0.f);
        if (WRVT && isv) {
          const int bb = row >> 11, ss = row & 2047;
          vtout[((size_t)(bb * 16 + hh) * 64 + dd) * 2048 + ss] = f2bf(v);
        } else if (OUTBF) {
          ((unsigned short*)Cout)[(size_t)row * ldc + col] = f2bf(v);
        } else {
          ((float*)Cout)[(size_t)row * ldc + col] = v;
        }
      }
    }
  }
}

// ---------------------------------------------------------------------------
// 128x128-tile GEMM (kept for N=1024 shapes): BK=32, 4 waves (2x2), 4x4 frags,
// now double-buffered 2-phase (stage T+1 before compute T, 1 barrier/tile)
// with the XCD-swizzled 1D grid.
// ---------------------------------------------------------------------------
template<bool BIAS, bool RELU, bool RESID, bool OUTBF>
__global__ __launch_bounds__(256) void gemm_bt(
    const unsigned short* __restrict__ A, const unsigned short* __restrict__ B,
    const float* __restrict__ bias, const float* __restrict__ resid,
    void* __restrict__ Cout, int M, int N, int K, int ldc, int nyt)
{
  __shared__ unsigned short Al[2][128 * 32];
  __shared__ unsigned short Bl[2][128 * 32];
  const int t = threadIdx.x;
  const int w = t >> 6, l = t & 63;
  const int wr = w >> 1, wc = w & 1;
  int2 tt = swz_tile((int)blockIdx.x, N >> 7, nyt);
  const int m0 = tt.x * 128, n0 = tt.y * 128;

  const int srow = w * 16 + (l >> 2);                         // + i*64
  const int scsw = ((l & 3) * 8) ^ (((srow >> 1) & 3) << 3);  // pre-swizzled col
  const unsigned short* Ab = A + (size_t)(m0 + srow) * K + scsw;
  const unsigned short* Bb = B + (size_t)(n0 + srow) * K + scsw;
  const int sdst = w * 512 + l * 8;                           // + i*2048

  auto STAGE = [&](int slot, int k0) {
#pragma unroll
    for (int i = 0; i < 2; ++i) {
      __builtin_amdgcn_global_load_lds(
          (const __attribute__((address_space(1))) void*)(Ab + (size_t)i * 64 * K + k0),
          (__attribute__((address_space(3))) void*)(&Al[slot][sdst + i * 2048]), 16, 0, 0);
      __builtin_amdgcn_global_load_lds(
          (const __attribute__((address_space(1))) void*)(Bb + (size_t)i * 64 * K + k0),
          (__attribute__((address_space(3))) void*)(&Bl[slot][sdst + i * 2048]), 16, 0, 0);
    }
  };

  const f4 fz = {0.f, 0.f, 0.f, 0.f};
  f4 acc[4][4];
#pragma unroll
  for (int i = 0; i < 4; ++i)
#pragma unroll
    for (int j = 0; j < 4; ++j) acc[i][j] = fz;

  const int NT = K >> 5;
  STAGE(0, 0);
  __syncthreads();

  for (int T = 0; T < NT; ++T) {
    if (T + 1 < NT) STAGE((T + 1) & 1, (T + 1) * 32);
    const int sl = T & 1;
    const int rdcol = ((l >> 4) * 8) ^ ((((l & 15) >> 1) & 3) << 3);
    bf8 af[4], bg[4];
#pragma unroll
    for (int am = 0; am < 4; ++am)
      af[am] = *(const bf8*)&Al[sl][(wr * 64 + am * 16 + (l & 15)) * 32 + rdcol];
#pragma unroll
    for (int bn = 0; bn < 4; ++bn)
      bg[bn] = *(const bf8*)&Bl[sl][(wc * 64 + bn * 16 + (l & 15)) * 32 + rdcol];
    __builtin_amdgcn_s_setprio(1);
#pragma unroll
    for (int am = 0; am < 4; ++am)
#pragma unroll
      for (int bn = 0; bn < 4; ++bn)
        acc[am][bn] = __builtin_amdgcn_mfma_f32_16x16x32_bf16(af[am], bg[bn], acc[am][bn], 0, 0, 0);
    __builtin_amdgcn_s_setprio(0);
    __syncthreads();
  }

#pragma unroll
  for (int bn = 0; bn < 4; ++bn) {
    const int col = n0 + wc * 64 + bn * 16 + (l & 15);
    float bv = 0.f;
    if (BIAS) bv = bias[col];
#pragma unroll
    for (int am = 0; am < 4; ++am) {
#pragma unroll
      for (int r = 0; r < 4; ++r) {
        const int row = m0 + wr * 64 + am * 16 + ((l >> 4) * 4) + r;
        float v = acc[am][bn][r] + bv;
        if (RELU) v = fmaxf(v, 0.f);
        if (RESID) v += resid[(size_t)row * ldc + col];
        if (OUTBF) ((unsigned short*)Cout)[(size_t)row * ldc + col] = f2bf(v);
        else       ((float*)Cout)[(size_t)row * ldc + col] = v;
      }
    }
  }
}

// ---------------------------------------------------------------------------
// Causal flash attention, swapped-operand 32x32 structure (unchanged).
// ---------------------------------------------------------------------------
__global__ __launch_bounds__(256, 2) void attn_kernel(
    const unsigned short* __restrict__ qk, const unsigned short* __restrict__ vt,
    unsigned short* __restrict__ ctx)
{
  __shared__ unsigned short Ks[2][64 * 64];   // [keys][kdim], XOR-swizzled
  __shared__ unsigned short Vs[2][64 * 64];   // [d][keys],   XOR-swizzled

  const int t = threadIdx.x;
  const int w = t >> 6, l = t & 63;
  const int hi = l >> 5, q = l & 31;
  const int qt = 15 - (int)blockIdx.x;        // heavy-first
  const int h = blockIdx.y, b = blockIdx.z;
  const int q0w = qt * 128 + w * 32;
  const unsigned short* qbase = qk + ((size_t)b * 2048) * 2048 + h * 64;
  const unsigned short* kbase = qbase + 1024;
  const unsigned short* vbase = vt + ((size_t)(b * 16 + h)) * 64 * 2048;

  bf8 qf[4];
#pragma unroll
  for (int ksl = 0; ksl < 4; ++ksl)
    qf[ksl] = *(const bf8*)(qbase + (size_t)(q0w + q) * 2048 + ksl * 16 + hi * 8);

  f16x oacc[2];
#pragma unroll
  for (int dn = 0; dn < 2; ++dn)
#pragma unroll
    for (int i = 0; i < 16; ++i) oacc[dn][i] = 0.f;
  float m_ = -1e30f, l_ = 0.f;

  const int nit = 2 * qt + 2;

  auto STAGE = [&](int buf, int it) {
#pragma unroll
    for (int s = 0; s < 2; ++s) {
      const int row = s * 32 + (t >> 3);
      const int cb = (t & 7) * 16;
      const int sb = cb ^ ((row & 7) << 4);
      __builtin_amdgcn_global_load_lds(
          (const __attribute__((address_space(1))) void*)
              (kbase + (size_t)(it * 64 + row) * 2048 + (sb >> 1)),
          (__attribute__((address_space(3))) void*)(&Ks[buf][row * 64 + (cb >> 1)]),
          16, 0, 0);
      __builtin_amdgcn_global_load_lds(
          (const __attribute__((address_space(1))) void*)
              (vbase + (size_t)row * 2048 + it * 64 + (sb >> 1)),
          (__attribute__((address_space(3))) void*)(&Vs[buf][row * 64 + (cb >> 1)]),
          16, 0, 0);
    }
  };

  STAGE(0, 0);
  __syncthreads();

  for (int it = 0; it < nit; ++it) {
    const int buf = it & 1;
    if (it + 1 < nit) STAGE(buf ^ 1, it + 1);
    const int kb0 = it * 64;

    if (kb0 <= q0w + 31) {
      const bool bdry = (kb0 + 63) > q0w;
#pragma unroll
      for (int sg = 0; sg < 2; ++sg) {
        f16x sacc;
#pragma unroll
        for (int i = 0; i < 16; ++i) sacc[i] = 0.f;
#pragma unroll
        for (int ksl = 0; ksl < 4; ++ksl) {
          const int row = sg * 32 + q;
          const int cb = ((ksl * 16 + hi * 8) * 2) ^ ((row & 7) << 4);
          bf8 kf = *(const bf8*)((const char*)&Ks[buf][row * 64] + cb);
          sacc = __builtin_amdgcn_mfma_f32_32x32x16_bf16(kf, qf[ksl], sacc, 0, 0, 0);
        }
        float p[16];
        if (bdry) {
#pragma unroll
          for (int i = 0; i < 16; ++i) {
            const int key = kb0 + sg * 32 + (i & 3) + 8 * (i >> 2) + 4 * hi;
            p[i] = (key <= q0w + q) ? sacc[i] : -1e30f;
          }
        } else {
#pragma unroll
          for (int i = 0; i < 16; ++i) p[i] = sacc[i];
        }
        float mx = p[0];
#pragma unroll
        for (int i = 1; i < 16; ++i) mx = fmaxf(mx, p[i]);
        mx = fmaxf(mx, __shfl_xor(mx, 32));
        const float mn = fmaxf(m_, mx);
        const float alpha = __expf(m_ - mn);
        m_ = mn;
        float rs = 0.f;
#pragma unroll
        for (int i = 0; i < 16; ++i) { p[i] = __expf(p[i] - mn); rs += p[i]; }
        rs += __shfl_xor(rs, 32);
        l_ = alpha * l_ + rs;
#pragma unroll
        for (int dn = 0; dn < 2; ++dn)
#pragma unroll
          for (int i = 0; i < 16; ++i) oacc[dn][i] *= alpha;

        unsigned int wds[8];
#pragma unroll
        for (int m = 0; m < 4; ++m) {
          wds[m * 2]     = pk2(p[4 * m], p[4 * m + 1]);
          wds[m * 2 + 1] = pk2(p[4 * m + 2], p[4 * m + 3]);
        }
#pragma unroll
        for (int kq = 0; kq < 2; ++kq) {
          unsigned int x0 = __shfl_xor((int)(hi ? wds[4 * kq]     : wds[4 * kq + 2]), 32);
          unsigned int x1 = __shfl_xor((int)(hi ? wds[4 * kq + 1] : wds[4 * kq + 3]), 32);
          unsigned int pw0 = hi ? x0 : wds[4 * kq];
          unsigned int pw1 = hi ? x1 : wds[4 * kq + 1];
          unsigned int pw2 = hi ? wds[4 * kq + 2] : x0;
          unsigned int pw3 = hi ? wds[4 * kq + 3] : x1;
          union { unsigned int u[4]; bf8 v; } pu;
          pu.u[0] = pw0; pu.u[1] = pw1; pu.u[2] = pw2; pu.u[3] = pw3;
          const bf8 pf = pu.v;
#pragma unroll
          for (int dn = 0; dn < 2; ++dn) {
            const int row = dn * 32 + q;
            const int cb = ((sg * 32 + kq * 16 + hi * 8) * 2) ^ ((row & 7) << 4);
            bf8 vf = *(const bf8*)((const char*)&Vs[buf][row * 64] + cb);
            oacc[dn] = __builtin_amdgcn_mfma_f32_32x32x16_bf16(vf, pf, oacc[dn], 0, 0, 0);
          }
        }
      }
    }
    __syncthreads();
  }

  const float inv = 1.0f / l_;
  unsigned short* crow = ctx + ((size_t)(b * 2048 + q0w + q)) * 1024 + h * 64;
#pragma unroll
  for (int dn = 0; dn < 2; ++dn)
#pragma unroll
    for (int m = 0; m < 4; ++m) {
      const int d0 = dn * 32 + 8 * m + 4 * hi;
      *(unsigned int*)(crow + d0)     = pk2(oacc[dn][4 * m] * inv, oacc[dn][4 * m + 1] * inv);
      *(unsigned int*)(crow + d0 + 2) = pk2(oacc[dn][4 * m + 2] * inv, oacc[dn][4 * m + 3] * inv);
    }
}

// ---------------------------------------------------------------------------
// LayerNorm over rows of 1024 fp32 -> bf16. One block per row.
// ---------------------------------------------------------------------------
__global__ __launch_bounds__(256) void ln_kernel(
    const float* __restrict__ x, const float* __restrict__ sc,
    const float* __restrict__ sh, unsigned short* __restrict__ out)
{
  const int row = blockIdx.x, t = threadIdx.x;
  float4 v = ((const float4*)x)[(size_t)row * 256 + t];
  float s = v.x + v.y + v.z + v.w;
  float q = v.x * v.x + v.y * v.y + v.z * v.z + v.w * v.w;
#pragma unroll
  for (int off = 1; off < 64; off <<= 1) {
    s += __shfl_xor(s, off);
    q += __shfl_xor(q, off);
  }
  __shared__ float red[8];
  const int w = t >> 6, l = t & 63;
  if (l == 0) { red[w] = s; red[4 + w] = q; }
  __syncthreads();
  s = red[0] + red[1] + red[2] + red[3];
  q = red[4] + red[5] + red[6] + red[7];
  const float mean = s * (1.0f / 1024.0f);
  const float var = q * (1.0f / 1024.0f) - mean * mean;
  const float rstd = rsqrtf(var + 1e-5f);
  float4 scv = ((const float4*)sc)[t];
  float4 shv = ((const float4*)sh)[t];
  uint2 p;
  p.x = pk2(scv.x * (v.x - mean) * rstd + shv.x, scv.y * (v.y - mean) * rstd + shv.y);
  p.y = pk2(scv.z * (v.z - mean) * rstd + shv.z, scv.w * (v.w - mean) * rstd + shv.w);
  ((uint2*)out)[(size_t)row * 256 + t] = p;
}

// fp32 -> bf16 (optionally scaled) conversion, 4 elems/thread
__global__ __launch_bounds__(256) void cvt_kernel(
    const float* __restrict__ src, unsigned short* __restrict__ dst,
    int n4, float scale)
{
  int i = blockIdx.x * 256 + threadIdx.x;
  const int stride = gridDim.x * 256;
  for (; i < n4; i += stride) {
    float4 v = ((const float4*)src)[i];
    uint2 p;
    p.x = pk2(v.x * scale, v.y * scale);
    p.y = pk2(v.z * scale, v.w * scale);
    ((uint2*)dst)[i] = p;
  }
}

// ---------------------------------------------------------------------------
extern "C" void kernel_launch(void* const* d_in, const int* in_sizes, int n_in,
                              void* d_out, int out_size, void* d_ws, size_t ws_size,
                              hipStream_t stream)
{
  const float* x    = (const float*)d_in[0];
  const float* wq   = (const float*)d_in[1];
  const float* wk   = (const float*)d_in[2];
  const float* wv   = (const float*)d_in[3];
  const float* wo   = (const float*)d_in[4];
  const float* bo   = (const float*)d_in[5];
  const float* ln1s = (const float*)d_in[6];
  const float* ln1b = (const float*)d_in[7];
  const float* ln2s = (const float*)d_in[8];
  const float* ln2b = (const float*)d_in[9];
  const float* w1   = (const float*)d_in[10];
  const float* b1   = (const float*)d_in[11];
  const float* w2   = (const float*)d_in[12];
  const float* b2   = (const float*)d_in[13];
  float* out = (float*)d_out;

  const int M = 4096; // B*S

  // workspace (~83 MB)
  unsigned short* ws   = (unsigned short*)d_ws;
  unsigned short* lnb  = ws;                              // [4096,1024]
  unsigned short* qkvw = lnb  + (size_t)4096 * 1024;      // [3072,1024] wq(.125)|wk|wv
  unsigned short* wob  = qkvw + (size_t)3072 * 1024;      // [1024,1024]
  unsigned short* w1b  = wob  + (size_t)1024 * 1024;      // [4096,1024]
  unsigned short* w2b  = w1b  + (size_t)4096 * 1024;      // [1024,4096]
  unsigned short* qkb  = w2b  + (size_t)4096 * 1024;      // [4096,2048] q|k; y1 [4096,4096]
  unsigned short* vtb  = qkb  + (size_t)4096 * 2048;      // [32,64,2048] V^T
  unsigned short* ctxb = vtb  + (size_t)32 * 64 * 2048;   // [4096,1024]
  float* hf = (float*)(ctxb + (size_t)4096 * 1024);       // [4096,1024] fp32

  // weight conversions (1/sqrt(64) folded into wq)
  cvt_kernel<<<1024, 256, 0, stream>>>(wq, qkvw,                       (1024 * 1024) / 4, 0.125f);
  cvt_kernel<<<1024, 256, 0, stream>>>(wk, qkvw + (size_t)1024 * 1024, (1024 * 1024) / 4, 1.0f);
  cvt_kernel<<<1024, 256, 0, stream>>>(wv, qkvw + (size_t)2048 * 1024, (1024 * 1024) / 4, 1.0f);
  cvt_kernel<<<1024, 256, 0, stream>>>(wo, wob,                        (1024 * 1024) / 4, 1.0f);
  cvt_kernel<<<2048, 256, 0, stream>>>(w1, w1b, (4096 * 1024) / 4, 1.0f);
  cvt_kernel<<<2048, 256, 0, stream>>>(w2, w2b, (4096 * 1024) / 4, 1.0f);

  // ln1 = LN(x)
  ln_kernel<<<M, 256, 0, stream>>>(x, ln1s, ln1b, lnb);
  // q|k -> qkb (stride 2048), v -> vtb transposed   [256^2 tile, 192 blocks]
  gemm_bt256<false, false, true, true><<<192, 512, 0, stream>>>(
      lnb, qkvw, nullptr, qkb, M, 3072, 1024, 2048, vtb, 16);
  // ctx = causal_attention(q,k,v)
  attn_kernel<<<dim3(16, 16, 2), 256, 0, stream>>>(qkb, vtb, ctxb);
  // h = x + ctx @ wo^T + bo   (fp32)   [128^2 tile]
  gemm_bt<true, false, true, false><<<256, 256, 0, stream>>>(
      ctxb, wob, bo, x, hf, M, 1024, 1024, 1024, 32);
  // ln2 = LN(h)
  ln_kernel<<<M, 256, 0, stream>>>(hf, ln2s, ln2b, lnb);
  // y1 = relu(ln2 @ w1^T + b1)  (bf16, reuses qkb region)  [256^2 tile]
  gemm_bt256<true, true, true, false><<<256, 512, 0, stream>>>(
      lnb, w1b, b1, qkb, M, 4096, 1024, 4096, nullptr, 16);
  // out = h + y1 @ w2^T + b2   [128^2 tile]
  gemm_bt<true, false, true, false><<<256, 256, 0, stream>>>(
      qkb, w2b, b2, hf, out, M, 1024, 4096, 1024, 32);
}

// Round 4
// 272.576 us; speedup vs baseline: 1.6115x; 1.0503x over previous
//
#include <hip/hip_runtime.h>
#include <hip/hip_bf16.h>

#define DEV __device__ __forceinline__

typedef __attribute__((ext_vector_type(8))) short bf8;    // 8 x bf16 (4 VGPRs)
typedef __attribute__((ext_vector_type(4))) float f4;     // 16x16 MFMA acc
typedef __attribute__((ext_vector_type(16))) float f16x;  // 32x32 MFMA acc

// bf16 conversion via intrinsics so the compiler can fuse pairs into
// v_cvt_pk_bf16_f32 (m240: hand-written bit-twiddle blocks the fusion).
DEV unsigned short f2bf(float f) {
  union { __hip_bfloat16 h; unsigned short u; } c;
  c.h = __float2bfloat16(f);
  return c.u;
}
DEV unsigned int pk2(float a, float b) {
  union { __hip_bfloat162 h; unsigned int u; } c;
  c.h = __hip_bfloat162(__float2bfloat16(a), __float2bfloat16(b));
  return c.u;
}

// XCD-aware bijective block swizzle + 4-wide N supertiling.
DEV int2 swz_tile(int ob, int nxt, int nyt) {
  const int nb = nxt * nyt;
  const int cpx = nb >> 3;
  const int W = (ob & 7) * cpx + (ob >> 3);
  const int scw = 4 * nyt;
  const int sc = W / scw, rem = W - sc * scw;
  return make_int2(rem >> 2, sc * 4 + (rem & 3));
}

// ---------------------------------------------------------------------------
// 256x256-tile GEMM: C[M,N] = A[M,K] @ B[N,K]^T (+bias)(+relu), bf16, f32 acc.
// 512 thr = 8 waves (2x4); per-wave 128x64 out = 8x4 16x16x32 MFMA frags.
// BK=64, 2 LDS slots, 2-phase double-buffer, 1 barrier/K-tile.
// WRVT: cols >= 2048 (V of QKV) written transposed to vtout [b*16+h][64][2048].
// ---------------------------------------------------------------------------
template<bool BIAS, bool RELU, bool OUTBF, bool WRVT>
__global__ __launch_bounds__(512, 2) void gemm_bt256(
    const unsigned short* __restrict__ A, const unsigned short* __restrict__ B,
    const float* __restrict__ bias, void* __restrict__ Cout,
    int M, int N, int K, int ldc, unsigned short* __restrict__ vtout, int nyt)
{
  __shared__ unsigned short Sl[2][2][256 * 64];   // [slot][A=0/B=1][row*64+col]
  const int t = threadIdx.x;
  const int w = t >> 6, l = t & 63;
  const int wr = w >> 2, wc = w & 3;              // 2 x 4 wave grid
  int2 tt = swz_tile((int)blockIdx.x, N >> 8, nyt);
  const int m0 = tt.x * 256, n0 = tt.y * 256;

  const int srow = w * 32 + (l >> 3);
  const int scol = 8 * ((l & 7) ^ (l >> 3));      // pre-swizzled elem col
  const unsigned short* Ab = A + (size_t)(m0 + srow) * K + scol;
  const unsigned short* Bb = B + (size_t)(n0 + srow) * K + scol;
  const int sdst = w * 2048 + l * 8;

  auto STAGE = [&](int slot, int kt) {
#pragma unroll
    for (int i = 0; i < 4; ++i) {
      __builtin_amdgcn_global_load_lds(
          (const __attribute__((address_space(1))) void*)(Ab + (size_t)i * 8 * K + kt * 64),
          (__attribute__((address_space(3))) void*)(&Sl[slot][0][sdst + i * 512]), 16, 0, 0);
      __builtin_amdgcn_global_load_lds(
          (const __attribute__((address_space(1))) void*)(Bb + (size_t)i * 8 * K + kt * 64),
          (__attribute__((address_space(3))) void*)(&Sl[slot][1][sdst + i * 512]), 16, 0, 0);
    }
  };

  const f4 fz = {0.f, 0.f, 0.f, 0.f};
  f4 acc[8][4];
#pragma unroll
  for (int i = 0; i < 8; ++i)
#pragma unroll
    for (int j = 0; j < 4; ++j) acc[i][j] = fz;

  const int NT = K >> 6;
  STAGE(0, 0);
  __syncthreads();

  for (int T = 0; T < NT; ++T) {
    if (T + 1 < NT) STAGE((T + 1) & 1, T + 1);
    const int sl = T & 1;
#pragma unroll
    for (int ks = 0; ks < 2; ++ks) {
      const int cb = (ks * 64 + ((l >> 4) * 16)) ^ ((l & 7) << 4);  // bytes in row
      bf8 af[8], bg[4];
#pragma unroll
      for (int m = 0; m < 8; ++m)
        af[m] = *(const bf8*)((const char*)&Sl[sl][0][(wr * 128 + m * 16 + (l & 15)) * 64] + cb);
#pragma unroll
      for (int n = 0; n < 4; ++n)
        bg[n] = *(const bf8*)((const char*)&Sl[sl][1][(wc * 64 + n * 16 + (l & 15)) * 64] + cb);
      __builtin_amdgcn_s_setprio(1);
#pragma unroll
      for (int m = 0; m < 8; ++m)
#pragma unroll
        for (int n = 0; n < 4; ++n)
          acc[m][n] = __builtin_amdgcn_mfma_f32_16x16x32_bf16(af[m], bg[n], acc[m][n], 0, 0, 0);
      __builtin_amdgcn_s_setprio(0);
    }
    __syncthreads();
  }

#pragma unroll
  for (int n = 0; n < 4; ++n) {
    const int col = n0 + wc * 64 + n * 16 + (l & 15);
    float bv = 0.f;
    if (BIAS) bv = bias[col];
    const bool isv = WRVT && (col >= 2048);
    const int hh = (col - 2048) >> 6, dd = (col - 2048) & 63;
#pragma unroll
    for (int m = 0; m < 8; ++m) {
#pragma unroll
      for (int r = 0; r < 4; ++r) {
        const int row = m0 + wr * 128 + m * 16 + ((l >> 4) * 4) + r;
        float v = acc[m][n][r] + bv;
        if (RELU) v = fmaxf(v, 0.f);
        if (WRVT && isv) {
          const int bb = row >> 11, ss = row & 2047;
          vtout[((size_t)(bb * 16 + hh) * 64 + dd) * 2048 + ss] = f2bf(v);
        } else if (OUTBF) {
          ((unsigned short*)Cout)[(size_t)row * ldc + col] = f2bf(v);
        } else {
          ((float*)Cout)[(size_t)row * ldc + col] = v;
        }
      }
    }
  }
}

// ---------------------------------------------------------------------------
// 128x128-tile GEMM (N=1024 shapes): BK=32, 4 waves (2x2), 4x4 frags,
// double-buffered 2-phase, XCD-swizzled 1D grid.
// ---------------------------------------------------------------------------
template<bool BIAS, bool RELU, bool RESID, bool OUTBF>
__global__ __launch_bounds__(256) void gemm_bt(
    const unsigned short* __restrict__ A, const unsigned short* __restrict__ B,
    const float* __restrict__ bias, const float* __restrict__ resid,
    void* __restrict__ Cout, int M, int N, int K, int ldc, int nyt)
{
  __shared__ unsigned short Al[2][128 * 32];
  __shared__ unsigned short Bl[2][128 * 32];
  const int t = threadIdx.x;
  const int w = t >> 6, l = t & 63;
  const int wr = w >> 1, wc = w & 1;
  int2 tt = swz_tile((int)blockIdx.x, N >> 7, nyt);
  const int m0 = tt.x * 128, n0 = tt.y * 128;

  const int srow = w * 16 + (l >> 2);
  const int scsw = ((l & 3) * 8) ^ (((srow >> 1) & 3) << 3);
  const unsigned short* Ab = A + (size_t)(m0 + srow) * K + scsw;
  const unsigned short* Bb = B + (size_t)(n0 + srow) * K + scsw;
  const int sdst = w * 512 + l * 8;

  auto STAGE = [&](int slot, int k0) {
#pragma unroll
    for (int i = 0; i < 2; ++i) {
      __builtin_amdgcn_global_load_lds(
          (const __attribute__((address_space(1))) void*)(Ab + (size_t)i * 64 * K + k0),
          (__attribute__((address_space(3))) void*)(&Al[slot][sdst + i * 2048]), 16, 0, 0);
      __builtin_amdgcn_global_load_lds(
          (const __attribute__((address_space(1))) void*)(Bb + (size_t)i * 64 * K + k0),
          (__attribute__((address_space(3))) void*)(&Bl[slot][sdst + i * 2048]), 16, 0, 0);
    }
  };

  const f4 fz = {0.f, 0.f, 0.f, 0.f};
  f4 acc[4][4];
#pragma unroll
  for (int i = 0; i < 4; ++i)
#pragma unroll
    for (int j = 0; j < 4; ++j) acc[i][j] = fz;

  const int NT = K >> 5;
  STAGE(0, 0);
  __syncthreads();

  for (int T = 0; T < NT; ++T) {
    if (T + 1 < NT) STAGE((T + 1) & 1, (T + 1) * 32);
    const int sl = T & 1;
    const int rdcol = ((l >> 4) * 8) ^ ((((l & 15) >> 1) & 3) << 3);
    bf8 af[4], bg[4];
#pragma unroll
    for (int am = 0; am < 4; ++am)
      af[am] = *(const bf8*)&Al[sl][(wr * 64 + am * 16 + (l & 15)) * 32 + rdcol];
#pragma unroll
    for (int bn = 0; bn < 4; ++bn)
      bg[bn] = *(const bf8*)&Bl[sl][(wc * 64 + bn * 16 + (l & 15)) * 32 + rdcol];
    __builtin_amdgcn_s_setprio(1);
#pragma unroll
    for (int am = 0; am < 4; ++am)
#pragma unroll
      for (int bn = 0; bn < 4; ++bn)
        acc[am][bn] = __builtin_amdgcn_mfma_f32_16x16x32_bf16(af[am], bg[bn], acc[am][bn], 0, 0, 0);
    __builtin_amdgcn_s_setprio(0);
    __syncthreads();
  }

#pragma unroll
  for (int bn = 0; bn < 4; ++bn) {
    const int col = n0 + wc * 64 + bn * 16 + (l & 15);
    float bv = 0.f;
    if (BIAS) bv = bias[col];
#pragma unroll
    for (int am = 0; am < 4; ++am) {
#pragma unroll
      for (int r = 0; r < 4; ++r) {
        const int row = m0 + wr * 64 + am * 16 + ((l >> 4) * 4) + r;
        float v = acc[am][bn][r] + bv;
        if (RELU) v = fmaxf(v, 0.f);
        if (RESID) v += resid[(size_t)row * ldc + col];
        if (OUTBF) ((unsigned short*)Cout)[(size_t)row * ldc + col] = f2bf(v);
        else       ((float*)Cout)[(size_t)row * ldc + col] = v;
      }
    }
  }
}

// ---------------------------------------------------------------------------
// Causal flash attention, swapped-operand 32x32, load-balanced pairing.
// 32 q-tiles of 64 rows; block j does tile (31-j) then tile j -> every block
// runs exactly 33 KV-iterations (perfect balance). Block = 128 thr = 2 waves,
// wave owns 32 queries. Merged softmax over 64 keys/iter + defer-max (T13).
// ---------------------------------------------------------------------------
__global__ __launch_bounds__(128, 2) void attn_kernel(
    const unsigned short* __restrict__ qk, const unsigned short* __restrict__ vt,
    unsigned short* __restrict__ ctx)
{
  __shared__ unsigned short Ks[2][64 * 64];   // [keys][kdim], XOR-swizzled
  __shared__ unsigned short Vs[2][64 * 64];   // [d][keys],   XOR-swizzled

  const int t = threadIdx.x;
  const int w = t >> 6, l = t & 63;
  const int hi = l >> 5, q = l & 31;
  const int j = blockIdx.x;
  const int h = blockIdx.y, b = blockIdx.z;
  const unsigned short* qbase = qk + ((size_t)b * 2048) * 2048 + h * 64;
  const unsigned short* kbase = qbase + 1024;
  const unsigned short* vbase = vt + ((size_t)(b * 16 + h)) * 64 * 2048;

  auto STAGE = [&](int buf, int it) {
#pragma unroll
    for (int s = 0; s < 4; ++s) {
      const int row = s * 16 + (t >> 3);
      const int cb = (t & 7) * 16;            // linear byte col in LDS
      const int sb = cb ^ ((row & 7) << 4);   // pre-swizzled global byte col
      __builtin_amdgcn_global_load_lds(
          (const __attribute__((address_space(1))) void*)
              (kbase + (size_t)(it * 64 + row) * 2048 + (sb >> 1)),
          (__attribute__((address_space(3))) void*)(&Ks[buf][row * 64 + (cb >> 1)]),
          16, 0, 0);
      __builtin_amdgcn_global_load_lds(
          (const __attribute__((address_space(1))) void*)
              (vbase + (size_t)row * 2048 + it * 64 + (sb >> 1)),
          (__attribute__((address_space(3))) void*)(&Vs[buf][row * 64 + (cb >> 1)]),
          16, 0, 0);
    }
  };

  for (int pass = 0; pass < 2; ++pass) {
    const int qtile = pass ? j : 31 - j;      // heavy pass first
    const int q0w = qtile * 64 + w * 32;
    bf8 qf[4];
#pragma unroll
    for (int ksl = 0; ksl < 4; ++ksl)
      qf[ksl] = *(const bf8*)(qbase + (size_t)(q0w + q) * 2048 + ksl * 16 + hi * 8);

    f16x oacc[2];
#pragma unroll
    for (int dn = 0; dn < 2; ++dn)
#pragma unroll
      for (int i = 0; i < 16; ++i) oacc[dn][i] = 0.f;
    float m_ = -1e30f, l_ = 0.f;

    const int nit = qtile + 1;
    STAGE(0, 0);
    __syncthreads();

    for (int it = 0; it < nit; ++it) {
      const int buf = it & 1;
      if (it + 1 < nit) STAGE(buf ^ 1, it + 1);
      const int kb0 = it * 64;

      // ---- S^T = K @ Q^T for 64 keys (two 32-key groups) ----
      f16x s0, s1;
#pragma unroll
      for (int i = 0; i < 16; ++i) { s0[i] = 0.f; s1[i] = 0.f; }
#pragma unroll
      for (int ksl = 0; ksl < 4; ++ksl) {
        const int cbq = ((ksl * 16 + hi * 8) * 2);
        const int r0 = q, r1 = 32 + q;
        bf8 k0 = *(const bf8*)((const char*)&Ks[buf][r0 * 64] + (cbq ^ ((r0 & 7) << 4)));
        bf8 k1 = *(const bf8*)((const char*)&Ks[buf][r1 * 64] + (cbq ^ ((r1 & 7) << 4)));
        s0 = __builtin_amdgcn_mfma_f32_32x32x16_bf16(k0, qf[ksl], s0, 0, 0, 0);
        s1 = __builtin_amdgcn_mfma_f32_32x32x16_bf16(k1, qf[ksl], s1, 0, 0, 0);
      }

      // ---- causal mask ----
      float p[32];
      if (kb0 + 63 > q0w) {
#pragma unroll
        for (int i = 0; i < 16; ++i) {
          const int key = kb0 + (i & 3) + 8 * (i >> 2) + 4 * hi;
          p[i]      = (key <= q0w + q)      ? s0[i] : -1e30f;
          p[16 + i] = (key + 32 <= q0w + q) ? s1[i] : -1e30f;
        }
      } else {
#pragma unroll
        for (int i = 0; i < 16; ++i) { p[i] = s0[i]; p[16 + i] = s1[i]; }
      }

      // ---- single softmax pass over 64 keys, defer-max THR=8 ----
      float tm[16];
#pragma unroll
      for (int i = 0; i < 16; ++i) tm[i] = fmaxf(p[i], p[16 + i]);
#pragma unroll
      for (int st = 8; st >= 1; st >>= 1)
#pragma unroll
        for (int i = 0; i < 8; ++i)
          if (i < st) tm[i] = fmaxf(tm[i], tm[i + st]);
      const float pmax = fmaxf(tm[0], __shfl_xor(tm[0], 32));
      if (__any(pmax > m_ + 8.0f)) {
        const float mn = fmaxf(m_, pmax);
        const float alpha = __expf(m_ - mn);
        m_ = mn;
        l_ *= alpha;
#pragma unroll
        for (int dn = 0; dn < 2; ++dn)
#pragma unroll
          for (int i = 0; i < 16; ++i) oacc[dn][i] *= alpha;
      }
#pragma unroll
      for (int i = 0; i < 32; ++i) p[i] = __expf(p[i] - m_);
      float ts[16];
#pragma unroll
      for (int i = 0; i < 16; ++i) ts[i] = p[i] + p[16 + i];
#pragma unroll
      for (int st = 8; st >= 1; st >>= 1)
#pragma unroll
        for (int i = 0; i < 8; ++i)
          if (i < st) ts[i] += ts[i + st];
      l_ += ts[0] + __shfl_xor(ts[0], 32);

      // ---- pack P (v_cvt_pk) + O^T += V^T @ P per 32-key group ----
#pragma unroll
      for (int sg = 0; sg < 2; ++sg) {
        const float* pp = p + sg * 16;
        unsigned int wds[8];
#pragma unroll
        for (int m = 0; m < 4; ++m) {
          wds[m * 2]     = pk2(pp[4 * m], pp[4 * m + 1]);
          wds[m * 2 + 1] = pk2(pp[4 * m + 2], pp[4 * m + 3]);
        }
#pragma unroll
        for (int kq = 0; kq < 2; ++kq) {
          unsigned int x0 = __shfl_xor((int)(hi ? wds[4 * kq]     : wds[4 * kq + 2]), 32);
          unsigned int x1 = __shfl_xor((int)(hi ? wds[4 * kq + 1] : wds[4 * kq + 3]), 32);
          union { unsigned int u[4]; bf8 v; } pu;
          pu.u[0] = hi ? x0 : wds[4 * kq];
          pu.u[1] = hi ? x1 : wds[4 * kq + 1];
          pu.u[2] = hi ? wds[4 * kq + 2] : x0;
          pu.u[3] = hi ? wds[4 * kq + 3] : x1;
          const bf8 pf = pu.v;
#pragma unroll
          for (int dn = 0; dn < 2; ++dn) {
            const int row = dn * 32 + q;
            const int cb = ((sg * 32 + kq * 16 + hi * 8) * 2) ^ ((row & 7) << 4);
            bf8 vf = *(const bf8*)((const char*)&Vs[buf][row * 64] + cb);
            oacc[dn] = __builtin_amdgcn_mfma_f32_32x32x16_bf16(vf, pf, oacc[dn], 0, 0, 0);
          }
        }
      }
      __syncthreads();
    }

    // epilogue: lane (hi,q) reg i of oacc[dn] = O^T[dn*32+(i&3)+8*(i>>2)+4hi][q]
    const float inv = 1.0f / l_;
    unsigned short* crow = ctx + ((size_t)(b * 2048 + q0w + q)) * 1024 + h * 64;
#pragma unroll
    for (int dn = 0; dn < 2; ++dn)
#pragma unroll
      for (int m = 0; m < 4; ++m) {
        const int d0 = dn * 32 + 8 * m + 4 * hi;
        *(unsigned int*)(crow + d0)     = pk2(oacc[dn][4 * m] * inv, oacc[dn][4 * m + 1] * inv);
        *(unsigned int*)(crow + d0 + 2) = pk2(oacc[dn][4 * m + 2] * inv, oacc[dn][4 * m + 3] * inv);
      }
  }
}

// ---------------------------------------------------------------------------
// LayerNorm over rows of 1024 fp32 -> bf16. One block per row.
// ---------------------------------------------------------------------------
__global__ __launch_bounds__(256) void ln_kernel(
    const float* __restrict__ x, const float* __restrict__ sc,
    const float* __restrict__ sh, unsigned short* __restrict__ out)
{
  const int row = blockIdx.x, t = threadIdx.x;
  float4 v = ((const float4*)x)[(size_t)row * 256 + t];
  float s = v.x + v.y + v.z + v.w;
  float q = v.x * v.x + v.y * v.y + v.z * v.z + v.w * v.w;
#pragma unroll
  for (int off = 1; off < 64; off <<= 1) {
    s += __shfl_xor(s, off);
    q += __shfl_xor(q, off);
  }
  __shared__ float red[8];
  const int w = t >> 6, l = t & 63;
  if (l == 0) { red[w] = s; red[4 + w] = q; }
  __syncthreads();
  s = red[0] + red[1] + red[2] + red[3];
  q = red[4] + red[5] + red[6] + red[7];
  const float mean = s * (1.0f / 1024.0f);
  const float var = q * (1.0f / 1024.0f) - mean * mean;
  const float rstd = rsqrtf(var + 1e-5f);
  float4 scv = ((const float4*)sc)[t];
  float4 shv = ((const float4*)sh)[t];
  uint2 p;
  p.x = pk2(scv.x * (v.x - mean) * rstd + shv.x, scv.y * (v.y - mean) * rstd + shv.y);
  p.y = pk2(scv.z * (v.z - mean) * rstd + shv.z, scv.w * (v.w - mean) * rstd + shv.w);
  ((uint2*)out)[(size_t)row * 256 + t] = p;
}

// ---------------------------------------------------------------------------
// Fused fp32->bf16 weight conversion: all 6 weight mats in one grid-stride
// kernel (dst regions are contiguous: qkvw|wob|w1b|w2b = 12M elems).
// wq gets the 1/sqrt(64)=0.125 softmax scale folded in.
// ---------------------------------------------------------------------------
__global__ __launch_bounds__(256) void cvt_weights(
    const float* __restrict__ wq, const float* __restrict__ wk,
    const float* __restrict__ wv, const float* __restrict__ wo,
    const float* __restrict__ w1, const float* __restrict__ w2,
    unsigned short* __restrict__ dst)
{
  const int M1 = 1 << 20;
  const int n4 = (12 * M1) / 4;
  const int stride = gridDim.x * 256;
  for (int i4 = blockIdx.x * 256 + threadIdx.x; i4 < n4; i4 += stride) {
    const size_t i = (size_t)i4 * 4;
    const int mi = (int)(i >> 20);
    const float* src;
    size_t off;
    float sc = 1.0f;
    if (mi < 4) {
      src = mi == 0 ? wq : mi == 1 ? wk : mi == 2 ? wv : wo;
      off = i & (size_t)(M1 - 1);
      if (mi == 0) sc = 0.125f;
    } else if (mi < 8) {
      src = w1; off = i - (size_t)4 * M1;
    } else {
      src = w2; off = i - (size_t)8 * M1;
    }
    float4 v = *(const float4*)(src + off);
    uint2 pq;
    pq.x = pk2(v.x * sc, v.y * sc);
    pq.y = pk2(v.z * sc, v.w * sc);
    ((uint2*)dst)[i4] = pq;
  }
}

// ---------------------------------------------------------------------------
extern "C" void kernel_launch(void* const* d_in, const int* in_sizes, int n_in,
                              void* d_out, int out_size, void* d_ws, size_t ws_size,
                              hipStream_t stream)
{
  const float* x    = (const float*)d_in[0];
  const float* wq   = (const float*)d_in[1];
  const float* wk   = (const float*)d_in[2];
  const float* wv   = (const float*)d_in[3];
  const float* wo   = (const float*)d_in[4];
  const float* bo   = (const float*)d_in[5];
  const float* ln1s = (const float*)d_in[6];
  const float* ln1b = (const float*)d_in[7];
  const float* ln2s = (const float*)d_in[8];
  const float* ln2b = (const float*)d_in[9];
  const float* w1   = (const float*)d_in[10];
  const float* b1   = (const float*)d_in[11];
  const float* w2   = (const float*)d_in[12];
  const float* b2   = (const float*)d_in[13];
  float* out = (float*)d_out;

  const int M = 4096; // B*S

  // workspace (~83 MB)
  unsigned short* ws   = (unsigned short*)d_ws;
  unsigned short* lnb  = ws;                              // [4096,1024]
  unsigned short* qkvw = lnb  + (size_t)4096 * 1024;      // [3072,1024] wq(.125)|wk|wv
  unsigned short* wob  = qkvw + (size_t)3072 * 1024;      // [1024,1024]
  unsigned short* w1b  = wob  + (size_t)1024 * 1024;      // [4096,1024]
  unsigned short* w2b  = w1b  + (size_t)4096 * 1024;      // [1024,4096]
  unsigned short* qkb  = w2b  + (size_t)4096 * 1024;      // [4096,2048] q|k; y1 [4096,4096]
  unsigned short* vtb  = qkb  + (size_t)4096 * 2048;      // [32,64,2048] V^T
  unsigned short* ctxb = vtb  + (size_t)32 * 64 * 2048;   // [4096,1024]
  float* hf = (float*)(ctxb + (size_t)4096 * 1024);       // [4096,1024] fp32

  // all weight conversions in one launch (dst = qkvw..w2b contiguous)
  cvt_weights<<<2048, 256, 0, stream>>>(wq, wk, wv, wo, w1, w2, qkvw);

  // ln1 = LN(x)
  ln_kernel<<<M, 256, 0, stream>>>(x, ln1s, ln1b, lnb);
  // q|k -> qkb (stride 2048), v -> vtb transposed   [256^2 tile]
  gemm_bt256<false, false, true, true><<<192, 512, 0, stream>>>(
      lnb, qkvw, nullptr, qkb, M, 3072, 1024, 2048, vtb, 16);
  // ctx = causal_attention(q,k,v)   [paired q-tiles, 2-wave blocks]
  attn_kernel<<<dim3(16, 16, 2), 128, 0, stream>>>(qkb, vtb, ctxb);
  // h = x + ctx @ wo^T + bo   (fp32)   [128^2 tile]
  gemm_bt<true, false, true, false><<<256, 256, 0, stream>>>(
      ctxb, wob, bo, x, hf, M, 1024, 1024, 1024, 32);
  // ln2 = LN(h)
  ln_kernel<<<M, 256, 0, stream>>>(hf, ln2s, ln2b, lnb);
  // y1 = relu(ln2 @ w1^T + b1)  (bf16, reuses qkb region)  [256^2 tile]
  gemm_bt256<true, true, true, false><<<256, 512, 0, stream>>>(
      lnb, w1b, b1, qkb, M, 4096, 1024, 4096, nullptr, 16);
  // out = h + y1 @ w2^T + b2   [128^2 tile]
  gemm_bt<true, false, true, false><<<256, 256, 0, stream>>>(
      qkb, w2b, b2, hf, out, M, 1024, 4096, 1024, 32);
}